// Round 1
// baseline (891.561 us; speedup 1.0000x reference)
//
#include <hip/hip_runtime.h>
#include <hip/hip_bf16.h>

// Problem constants
#define NROWS   32768     // 32*32*32
#define DIMD    256
#define NATOMS  1024
#define SPAR    8

// ---------------------------------------------------------------------------
// dict atom squared norms
__global__ void vq_norms(const float* __restrict__ dict_w, float* __restrict__ dnorm) {
    int k = blockIdx.x;          // 1024 blocks
    int lane = threadIdx.x;      // 64 threads
    float4 v = *(const float4*)&dict_w[(size_t)k * DIMD + lane * 4];
    float s = v.x * v.x + v.y * v.y + v.z * v.z + v.w * v.w;
#pragma unroll
    for (int o = 32; o > 0; o >>= 1) s += __shfl_down(s, o, 64);
    if (lane == 0) dnorm[k] = s;
}

// ---------------------------------------------------------------------------
// top-8 insert into sorted (ascending) register array. key = sortable(dist)<<32 | idx
__device__ __forceinline__ void top8_insert(unsigned long long ck, float cl,
                                            unsigned long long (&key)[8], float (&lg)[8]) {
    bool b[8];
#pragma unroll
    for (int j = 0; j < 8; ++j) b[j] = ck < key[j];
#pragma unroll
    for (int j = 7; j >= 1; --j) {
        unsigned long long t = b[j - 1] ? key[j - 1] : ck;
        float tl = b[j - 1] ? lg[j - 1] : cl;
        key[j] = b[j] ? t : key[j];
        lg[j]  = b[j] ? tl : lg[j];
    }
    key[0] = b[0] ? ck : key[0];
    lg[0]  = b[0] ? cl : lg[0];
}

// ---------------------------------------------------------------------------
// Main fused kernel: dual GEMM (logits + dots) + online softmax-sum + online top-8
// 64 rows x 1024 atoms per block, 256 threads, 512 blocks.
__global__ __launch_bounds__(256, 2) void vq_main(
    const float* __restrict__ z_e, const float* __restrict__ dict_w,
    const float* __restrict__ rep_w, const float* __restrict__ rep_b,
    const float* __restrict__ dnorm,
    float* __restrict__ rep_sparse, int* __restrict__ idx_out,
    float* __restrict__ w_out, int* __restrict__ counts)
{
    __shared__ __align__(16) char smem[61952];
    auto As = reinterpret_cast<float (*)[64]>(smem);            // [32][64]   8192 B
    auto Rs = reinterpret_cast<float (*)[36]>(smem + 8192);     // [64][36]   9216 B
    auto Ws = reinterpret_cast<float (*)[36]>(smem + 17408);    // [64][36]   9216 B
    auto Ll = reinterpret_cast<float (*)[69]>(smem + 26624);    // [64][69]  17664 B (logits)
    auto Ld = reinterpret_cast<float (*)[69]>(smem + 44288);    // [64][69]  17664 B (sel values)
    // end-of-kernel overlay (re-uses As/Rs/Ws space, barrier separated):
    unsigned long long* mk = reinterpret_cast<unsigned long long*>(smem);  // [64][4][8] 16384 B
    float* ml   = reinterpret_cast<float*>(smem + 16384);                  // [64][4][8]  8192 B
    float* msum = reinterpret_cast<float*>(smem + 24576);                  // [64][4]     1024 B

    const int tid = threadIdx.x;
    const int row0 = blockIdx.x * 64;
    const int bb  = row0 >> 10;          // batch index (64 | 1024, no straddle)
    const int hw0 = row0 & 1023;
    const float* zbase = z_e + (size_t)bb * (DIMD * 1024) + hw0;

    // selection state: thread = (row selr, part selp); part scans 16 atoms per tile
    const int selr = tid & 63, selp = tid >> 6;
    unsigned long long key[8];
    float lg[8];
    float sume = 0.f;
#pragma unroll
    for (int j = 0; j < 8; ++j) { key[j] = ~0ull; lg[j] = 0.f; }

    // GEMM thread mapping: 16 row-tiles x 16 atom-tiles of 4x4
    const int tm = tid & 15, tk = tid >> 4;
    const int am = tm * 4, ak = tk * 4;

    for (int kt = 0; kt < 16; ++kt) {
        const int k0 = kt * 64;
        float accR[4][4] = {{0}}, accW[4][4] = {{0}};

        for (int d0 = 0; d0 < DIMD; d0 += 32) {
            __syncthreads();
            {   // stage A tile (transposed [d][m]); coalesced 64-float rows
                int m = tid & 63, dd = tid >> 6;
#pragma unroll
                for (int it = 0; it < 8; ++it)
                    As[dd + it * 4][m] = zbase[(size_t)(d0 + dd + it * 4) * 1024 + m];
            }
            {   // stage rep_w / dict_w tiles [k][d], float4 coalesced
                int k = tid >> 3, dq = (tid & 7) * 4;
#pragma unroll
                for (int it = 0; it < 2; ++it) {
                    int kk = k + it * 32;
                    *(float4*)&Rs[kk][dq] = *(const float4*)&rep_w[(size_t)(k0 + kk) * DIMD + d0 + dq];
                    *(float4*)&Ws[kk][dq] = *(const float4*)&dict_w[(size_t)(k0 + kk) * DIMD + d0 + dq];
                }
            }
            __syncthreads();
#pragma unroll
            for (int d = 0; d < 32; d += 4) {
                float4 av[4], rv[4], wv[4];
#pragma unroll
                for (int u = 0; u < 4; ++u) av[u] = *(const float4*)&As[d + u][am];
#pragma unroll
                for (int j = 0; j < 4; ++j) {
                    rv[j] = *(const float4*)&Rs[ak + j][d];
                    wv[j] = *(const float4*)&Ws[ak + j][d];
                }
#pragma unroll
                for (int u = 0; u < 4; ++u) {
#pragma unroll
                    for (int i = 0; i < 4; ++i) {
                        float a = ((const float*)&av[u])[i];
#pragma unroll
                        for (int j = 0; j < 4; ++j) {
                            accR[i][j] = fmaf(a, ((const float*)&rv[j])[u], accR[i][j]);
                            accW[i][j] = fmaf(a, ((const float*)&wv[j])[u], accW[i][j]);
                        }
                    }
                }
            }
        }

        // publish tile results (logit with bias; selection value = ||dict||^2 - 2*dot)
#pragma unroll
        for (int i = 0; i < 4; ++i)
#pragma unroll
            for (int j = 0; j < 4; ++j) {
                int gk = k0 + ak + j;
                Ll[am + i][ak + j] = accR[i][j] + rep_b[gk];
                Ld[am + i][ak + j] = dnorm[gk] - 2.0f * accW[i][j];
            }
        __syncthreads();

        // online scan: each of 4 parts per row handles 16 atoms
        for (int t = 0; t < 16; ++t) {
            int kl = selp * 16 + t;
            float l = Ll[selr][kl];
            float v = Ld[selr][kl];
            sume += expf(l);
            unsigned int u = __float_as_uint(v);
            u = u ^ ((unsigned)((int)u >> 31) | 0x80000000u);   // monotone sortable
            unsigned long long ck = ((unsigned long long)u << 32) | (unsigned)(k0 + kl);
            if (ck < key[7]) top8_insert(ck, l, key, lg);
        }
    }

    // merge the 4 partial top-8s per row, finish softmax, scatter outputs
    __syncthreads();
    {
        int o = (selr * 4 + selp) * 8;
#pragma unroll
        for (int j = 0; j < 8; ++j) { mk[o + j] = key[j]; ml[o + j] = lg[j]; }
        msum[selr * 4 + selp] = sume;
    }
    __syncthreads();
    if (tid < 64) {
        int r = tid;
        unsigned long long K[8];
        float L[8];
#pragma unroll
        for (int j = 0; j < 8; ++j) { K[j] = mk[(r * 4 + 0) * 8 + j]; L[j] = ml[(r * 4 + 0) * 8 + j]; }
        for (int p = 1; p < 4; ++p)
            for (int t = 0; t < 8; ++t) {
                unsigned long long ck = mk[(r * 4 + p) * 8 + t];
                float cl = ml[(r * 4 + p) * 8 + t];
                if (ck < K[7]) top8_insert(ck, cl, K, L);
            }
        float s = msum[r * 4] + msum[r * 4 + 1] + msum[r * 4 + 2] + msum[r * 4 + 3];
        float inv = 0.125f / s;   // rep / SPARSITY
        int row = row0 + r;
#pragma unroll
        for (int j = 0; j < 8; ++j) {
            int gidx = (int)(K[j] & 0xffffffffull);
            float wv = expf(L[j]) * inv;
            idx_out[row * 8 + j] = gidx;
            w_out[row * 8 + j] = wv;
            rep_sparse[(size_t)row * NATOMS + gidx] = wv;
            atomicAdd(&counts[gidx], 1);
        }
    }
}

// ---------------------------------------------------------------------------
// Reconstruct z_dl, write z_st (NCHW), accumulate squared-error partials.
// 32 rows per block, 1024 blocks, 256 threads.
__global__ __launch_bounds__(256, 2) void vq_recon(
    const float* __restrict__ z_e, const float* __restrict__ dict_w,
    const int* __restrict__ idx_in, const float* __restrict__ w_in,
    float* __restrict__ z_st, float* __restrict__ partials)
{
    __shared__ float zdl[32][257];
    __shared__ float red[256];
    const int tid = threadIdx.x;
    const int row0 = blockIdx.x * 32;

    // phase A: z_dl rows into LDS; lanes over d (coalesced dict reads)
    for (int r = 0; r < 32; ++r) {
        int row = row0 + r;
        float acc = 0.f;
#pragma unroll
        for (int j = 0; j < 8; ++j) {
            int ix = idx_in[row * 8 + j];
            float wv = w_in[row * 8 + j];
            acc = fmaf(wv, dict_w[(size_t)ix * DIMD + tid], acc);
        }
        zdl[r][tid] = acc;
    }
    __syncthreads();

    // phase B: coalesced NCHW read/write; lanes over rows
    const int bb = row0 >> 10, hw0 = row0 & 1023;
    const float* zb = z_e + (size_t)bb * (DIMD * 1024) + hw0;
    float* ob = z_st + (size_t)bb * (DIMD * 1024) + hw0;
    const int m = tid & 31, dg = tid >> 5;     // 8 d-groups
    float sacc = 0.f;
    for (int it = 0; it < 32; ++it) {
        int d = it * 8 + dg;
        float ze = zb[(size_t)d * 1024 + m];
        float zd = zdl[m][d];
        float diff = zd - ze;
        ob[(size_t)d * 1024 + m] = ze + diff;   // straight-through value, ref rounding path
        sacc = fmaf(diff, diff, sacc);
    }
    red[tid] = sacc;
    __syncthreads();
    for (int s = 128; s > 0; s >>= 1) {
        if (tid < s) red[tid] += red[tid + s];
        __syncthreads();
    }
    if (tid == 0) partials[blockIdx.x] = red[0];
}

// ---------------------------------------------------------------------------
// Finalize: loss and perplexity (deterministic fixed-order reductions)
__global__ void vq_final(const float* __restrict__ partials,
                         const int* __restrict__ counts,
                         float* __restrict__ out_loss, float* __restrict__ out_perp)
{
    __shared__ double dred[256];
    __shared__ float fred[256];
    const int tid = threadIdx.x;
    double s = 0.0;
    for (int i = tid; i < 1024; i += 256) s += (double)partials[i];
    dred[tid] = s;
    __syncthreads();
    for (int st = 128; st > 0; st >>= 1) {
        if (tid < st) dred[tid] += dred[tid + st];
        __syncthreads();
    }
    float ps = 0.f;
    for (int i = tid; i < NATOMS; i += 256) {
        float p = (float)counts[i] * (1.0f / 262144.0f);   // counts/(8N), exact
        ps += p * logf(p + 1e-10f);
    }
    fred[tid] = ps;
    __syncthreads();
    for (int st = 128; st > 0; st >>= 1) {
        if (tid < st) fred[tid] += fred[tid + st];
        __syncthreads();
    }
    if (tid == 0) {
        *out_loss = 0.25f * (float)(dred[0] / 8388608.0);
        *out_perp = expf(-fred[0]);
    }
}

// ---------------------------------------------------------------------------
extern "C" void kernel_launch(void* const* d_in, const int* in_sizes, int n_in,
                              void* d_out, int out_size, void* d_ws, size_t ws_size,
                              hipStream_t stream) {
    const float* z_e    = (const float*)d_in[0];
    const float* dict_w = (const float*)d_in[1];
    const float* rep_w  = (const float*)d_in[2];
    const float* rep_b  = (const float*)d_in[3];

    float* out = (float*)d_out;
    float* out_loss   = out;                      // [0]
    float* z_st       = out + 1;                  // [1 .. 8388608]
    float* out_perp   = out + 1 + 8388608;        // [8388609]
    float* rep_sparse = out + 2 + 8388608;        // [8388610 ..]

    char* ws = (char*)d_ws;
    int*   idx_out  = (int*)ws;                             // 1 MB
    float* w_out    = (float*)(ws + (1 << 20));             // 1 MB
    int*   counts   = (int*)(ws + (2 << 20));               // 4 KB
    float* dnorm    = (float*)(ws + (2 << 20) + 4096);      // 4 KB
    float* partials = (float*)(ws + (2 << 20) + 8192);      // 4 KB

    hipMemsetAsync(rep_sparse, 0, (size_t)NROWS * NATOMS * sizeof(float), stream);
    hipMemsetAsync(counts, 0, NATOMS * sizeof(int), stream);

    vq_norms<<<NATOMS, 64, 0, stream>>>(dict_w, dnorm);
    vq_main<<<NROWS / 64, 256, 0, stream>>>(z_e, dict_w, rep_w, rep_b, dnorm,
                                            rep_sparse, idx_out, w_out, counts);
    vq_recon<<<NROWS / 32, 256, 0, stream>>>(z_e, dict_w, idx_out, w_out, z_st, partials);
    vq_final<<<1, 256, 0, stream>>>(partials, counts, out_loss, out_perp);
}